// Round 18
// baseline (450.970 us; speedup 1.0000x reference)
//
#include <hip/hip_runtime.h>

constexpr int D = 128;
constexpr int BSHIFT = 9;               // 512 nodes per bucket
constexpr int BNODES = 1 << BSHIFT;
constexpr int NBUCK_MAX = 256;          // n=100000 -> 196 buckets
constexpr int LP = 136;                 // LDS row pitch in shorts (128 + 8 pad)
using short8 = __attribute__((ext_vector_type(8))) short;
using f32x4  = __attribute__((ext_vector_type(4))) float;

__device__ __forceinline__ unsigned rneb(float f) {
    unsigned u = __float_as_uint(f);
    return (u + 0x7fffu + ((u >> 16) & 1u)) >> 16;   // bf16 bits (RNE)
}
__device__ __forceinline__ float lo2f(unsigned u) { return __uint_as_float(u << 16); }
__device__ __forceinline__ float hi2f(unsigned u) { return __uint_as_float(u & 0xffff0000u); }

// ---------------------------------------------------------------------------
// Round-12 proven housekeeping: blocks [0,32) pack weight fragments; block 32
// zeroes bcnt; blocks [32, 32+cvt) convert x to bf16.
__global__ __launch_bounds__(256) void misc_kernel(
    const float* __restrict__ w1l, const float* __restrict__ w1r,
    const float* __restrict__ w2l, const float* __restrict__ w2r,
    unsigned short* __restrict__ wf,
    const float* __restrict__ x, unsigned short* __restrict__ xb, int n4,
    int* __restrict__ bcnt)
{
    if (blockIdx.x < 32) {
        int t = blockIdx.x * 256 + threadIdx.x;          // 8192 threads
        int m = t >> 11;
        int r = t & 2047;                                 // f*64 + lane
        int f = r >> 6, lane = r & 63;
        int c = f >> 2, ks = f & 3;
        int col = c * 16 + (lane & 15);
        int k0 = ks * 32 + (lane >> 4) * 8;
        const float* W = (m == 0) ? w1l : (m == 1) ? w1r : (m == 2) ? w2l : w2r;
        unsigned short o[8];
#pragma unroll
        for (int i = 0; i < 8; ++i) o[i] = (unsigned short)rneb(W[col * D + k0 + i]);
        uint4 pk;
        pk.x = o[0] | ((unsigned)o[1] << 16);
        pk.y = o[2] | ((unsigned)o[3] << 16);
        pk.z = o[4] | ((unsigned)o[5] << 16);
        pk.w = o[6] | ((unsigned)o[7] << 16);
        reinterpret_cast<uint4*>(wf)[t] = pk;
        return;
    }
    if (blockIdx.x == 32) bcnt[threadIdx.x] = 0;          // NBUCK_MAX == 256
    int i = (blockIdx.x - 32) * 256 + threadIdx.x;
    if (i >= n4) return;
    float4 v = reinterpret_cast<const float4*>(x)[i];
    uint2 o;
    o.x = rneb(v.x) | (rneb(v.y) << 16);
    o.y = rneb(v.z) | (rneb(v.w) << 16);
    reinterpret_cast<uint2*>(xb)[i] = o;
}

// ---------------------------------------------------------------------------
// CSR build, round-12 proven path.
__global__ __launch_bounds__(256) void bucket_count(
    const int* __restrict__ dstI, int* __restrict__ bcnt, int E, int nb)
{
    __shared__ int lh[NBUCK_MAX];
    const int t = threadIdx.x;
    const int e0 = blockIdx.x * 4096;
    for (int i = t; i < nb; i += 256) lh[i] = 0;
    __syncthreads();
#pragma unroll
    for (int q = 0; q < 16; ++q) {
        int e = e0 + q * 256 + t;
        if (e < E) atomicAdd(&lh[dstI[e] >> BSHIFT], 1);
    }
    __syncthreads();
    for (int b = t; b < nb; b += 256)
        if (lh[b] > 0) atomicAdd(&bcnt[b], lh[b]);
}

__global__ __launch_bounds__(256) void bucket_scan(
    const int* __restrict__ bcnt, int* __restrict__ bbase,
    int* __restrict__ gcursor, int nb)
{
    __shared__ int tmp[256];
    const int t = threadIdx.x;
    const int v = (t < nb) ? bcnt[t] : 0;
    tmp[t] = v;
    __syncthreads();
    for (int off = 1; off < 256; off <<= 1) {
        int u = (t >= off) ? tmp[t - off] : 0;
        __syncthreads();
        tmp[t] += u;
        __syncthreads();
    }
    int excl = tmp[t] - v;
    if (t < nb) { bbase[t] = excl; gcursor[t] = excl; }
    if (t == nb - 1) bbase[nb] = excl + v;
}

__global__ __launch_bounds__(256) void bin_kernel(
    const int* __restrict__ srcI, const int* __restrict__ dstI,
    int* __restrict__ gcursor, unsigned* __restrict__ binned, int E, int nb)
{
    __shared__ int lhist[NBUCK_MAX];
    __shared__ int lbase[NBUCK_MAX];
    __shared__ int lcnt[NBUCK_MAX];
    const int t = threadIdx.x;
    const int e0 = blockIdx.x * 4096;
    for (int i = t; i < nb; i += 256) { lhist[i] = 0; lcnt[i] = 0; }
    __syncthreads();

    int dcache[16], scache[16];
#pragma unroll
    for (int q = 0; q < 16; ++q) {
        int e = e0 + q * 256 + t;
        int d = (e < E) ? dstI[e] : -1;
        dcache[q] = d;
        scache[q] = (e < E) ? srcI[e] : 0;
        if (d >= 0) atomicAdd(&lhist[d >> BSHIFT], 1);
    }
    __syncthreads();
    for (int b = t; b < nb; b += 256)
        if (lhist[b] > 0) lbase[b] = atomicAdd(&gcursor[b], lhist[b]);
    __syncthreads();
#pragma unroll
    for (int q = 0; q < 16; ++q) {
        int d = dcache[q];
        if (d >= 0) {
            int b = d >> BSHIFT;
            int off = atomicAdd(&lcnt[b], 1);
            binned[lbase[b] + off] =
                (unsigned)scache[q] | ((unsigned)(d & (BNODES - 1)) << 17);
        }
    }
}

__global__ __launch_bounds__(256) void bucket_build(
    const unsigned* __restrict__ binned, const int* __restrict__ bbase,
    int* __restrict__ rowptr, int* __restrict__ sorted_src, int n, int E)
{
    __shared__ int hist[BNODES];
    __shared__ int cur[BNODES];
    __shared__ int tmp[256];
    const int t = threadIdx.x;
    const int b = blockIdx.x;
    const int node0 = b << BSHIFT;
    const int ebeg = bbase[b];
    const int eend = bbase[b + 1];

    hist[t] = 0; hist[t + 256] = 0;
    __syncthreads();
    for (int e = ebeg + t; e < eend; e += 256)
        atomicAdd(&hist[(binned[e] >> 17) & (BNODES - 1)], 1);
    __syncthreads();

    const int v0 = hist[2 * t], v1 = hist[2 * t + 1];
    const int s = v0 + v1;
    tmp[t] = s;
    __syncthreads();
    for (int off = 1; off < 256; off <<= 1) {
        int u = (t >= off) ? tmp[t - off] : 0;
        __syncthreads();
        tmp[t] += u;
        __syncthreads();
    }
    const int pre = ebeg + tmp[t] - s;       // exclusive prefix of node 2t
    const int i0 = node0 + 2 * t, i1 = i0 + 1;
    cur[2 * t] = pre;
    cur[2 * t + 1] = pre + v0;
    if (i0 < n) rowptr[i0] = pre;
    if (i1 < n) rowptr[i1] = pre + v0;
    if (b == 0 && t == 0) rowptr[n] = E;
    __syncthreads();

    for (int e = ebeg + t; e < eend; e += 256) {
        unsigned w = binned[e];
        int pos = atomicAdd(&cur[(w >> 17) & (BNODES - 1)], 1);
        sorted_src[pos] = (int)(w & 0x1FFFF);
    }
}

// ---------------------------------------------------------------------------
// Fused SAGE layer: per block of 64 nodes, 4 waves.
// Phase 1 (per wave): aggregate means of its 16 nodes into an LDS tile
//   (round-12 proven gather loop; bf16 mean, padded pitch LP=136).
// Phase 2 (per wave): MFMA sweep; A(mean) fragments from LDS, A(self) from
//   global feat, B fragments from packed wf. No inter-wave LDS sharing ->
//   no __syncthreads between phases.
// mode 0: out = relu(...) -> bf16 outb.   mode 1: project to 4 dims -> outp.
__global__ __launch_bounds__(256) void fused_layer(
    const unsigned short* __restrict__ feat,   // gather AND self input
    const int* __restrict__ sorted_src, const int* __restrict__ rowptr,
    const unsigned short* __restrict__ wfL, const unsigned short* __restrict__ wfR,
    const float* __restrict__ bL,
    unsigned short* __restrict__ outb,         // mode 0 output
    const float* __restrict__ w_out, const float* __restrict__ b_out,
    float* __restrict__ outp,                  // mode 1 output
    int n, int mode)
{
    __shared__ unsigned short meanT[64 * LP];  // 17 KB, padded rows
    __shared__ float wsm[4 * D];
    wsm[threadIdx.x] = w_out[threadIdx.x];
    wsm[threadIdx.x + 256] = w_out[threadIdx.x + 256];
    __syncthreads();

    const int wave = threadIdx.x >> 6;
    const int lane = threadIdx.x & 63;
    const int row0 = blockIdx.x * 64 + wave * 16;

    // ---- Phase 1: aggregate 16 node means into meanT ----
    {
        const int sub = lane >> 4;
        const int part = lane & 15;
        for (int r = 0; r < 16; ++r) {
            int node = row0 + r;
            if (node > n - 1) node = n - 1;
            const int beg = rowptr[node];
            const int end = rowptr[node + 1];
            const int deg = end - beg;

            float acc[8];
#pragma unroll
            for (int j = 0; j < 8; ++j) acc[j] = 0.f;

            int e = beg;
            for (; e + 16 <= end; e += 16) {
                const int s0 = sorted_src[e + sub];
                const int s1 = sorted_src[e + 4 + sub];
                const int s2 = sorted_src[e + 8 + sub];
                const int s3 = sorted_src[e + 12 + sub];
                const uint4 v0 = *reinterpret_cast<const uint4*>(feat + (size_t)s0 * D + part * 8);
                const uint4 v1 = *reinterpret_cast<const uint4*>(feat + (size_t)s1 * D + part * 8);
                const uint4 v2 = *reinterpret_cast<const uint4*>(feat + (size_t)s2 * D + part * 8);
                const uint4 v3 = *reinterpret_cast<const uint4*>(feat + (size_t)s3 * D + part * 8);
                acc[0] += lo2f(v0.x); acc[1] += hi2f(v0.x);
                acc[2] += lo2f(v0.y); acc[3] += hi2f(v0.y);
                acc[4] += lo2f(v0.z); acc[5] += hi2f(v0.z);
                acc[6] += lo2f(v0.w); acc[7] += hi2f(v0.w);
                acc[0] += lo2f(v1.x); acc[1] += hi2f(v1.x);
                acc[2] += lo2f(v1.y); acc[3] += hi2f(v1.y);
                acc[4] += lo2f(v1.z); acc[5] += hi2f(v1.z);
                acc[6] += lo2f(v1.w); acc[7] += hi2f(v1.w);
                acc[0] += lo2f(v2.x); acc[1] += hi2f(v2.x);
                acc[2] += lo2f(v2.y); acc[3] += hi2f(v2.y);
                acc[4] += lo2f(v2.z); acc[5] += hi2f(v2.z);
                acc[6] += lo2f(v2.w); acc[7] += hi2f(v2.w);
                acc[0] += lo2f(v3.x); acc[1] += hi2f(v3.x);
                acc[2] += lo2f(v3.y); acc[3] += hi2f(v3.y);
                acc[4] += lo2f(v3.z); acc[5] += hi2f(v3.z);
                acc[6] += lo2f(v3.w); acc[7] += hi2f(v3.w);
            }
            if (e + 8 <= end) {
                const int s0 = sorted_src[e + sub];
                const int s1 = sorted_src[e + 4 + sub];
                const uint4 v0 = *reinterpret_cast<const uint4*>(feat + (size_t)s0 * D + part * 8);
                const uint4 v1 = *reinterpret_cast<const uint4*>(feat + (size_t)s1 * D + part * 8);
                acc[0] += lo2f(v0.x); acc[1] += hi2f(v0.x);
                acc[2] += lo2f(v0.y); acc[3] += hi2f(v0.y);
                acc[4] += lo2f(v0.z); acc[5] += hi2f(v0.z);
                acc[6] += lo2f(v0.w); acc[7] += hi2f(v0.w);
                acc[0] += lo2f(v1.x); acc[1] += hi2f(v1.x);
                acc[2] += lo2f(v1.y); acc[3] += hi2f(v1.y);
                acc[4] += lo2f(v1.z); acc[5] += hi2f(v1.z);
                acc[6] += lo2f(v1.w); acc[7] += hi2f(v1.w);
                e += 8;
            }
            if (e + 4 <= end) {
                const int s0 = sorted_src[e + sub];
                const uint4 v0 = *reinterpret_cast<const uint4*>(feat + (size_t)s0 * D + part * 8);
                acc[0] += lo2f(v0.x); acc[1] += hi2f(v0.x);
                acc[2] += lo2f(v0.y); acc[3] += hi2f(v0.y);
                acc[4] += lo2f(v0.z); acc[5] += hi2f(v0.z);
                acc[6] += lo2f(v0.w); acc[7] += hi2f(v0.w);
                e += 4;
            }
            if (e < end) {
                const int ei = e + sub;
                const bool act = ei < end;
                const int s = act ? sorted_src[ei] : sorted_src[beg];
                const float m = act ? 1.f : 0.f;
                const uint4 v = *reinterpret_cast<const uint4*>(feat + (size_t)s * D + part * 8);
                acc[0] += m * lo2f(v.x); acc[1] += m * hi2f(v.x);
                acc[2] += m * lo2f(v.y); acc[3] += m * hi2f(v.y);
                acc[4] += m * lo2f(v.z); acc[5] += m * hi2f(v.z);
                acc[6] += m * lo2f(v.w); acc[7] += m * hi2f(v.w);
            }

#pragma unroll
            for (int j = 0; j < 8; ++j) {
                acc[j] += __shfl_xor(acc[j], 16);
                acc[j] += __shfl_xor(acc[j], 32);
            }

            if (sub == 0) {
                const float inv = (deg > 0) ? 1.0f / (float)deg : 0.f;
                uint4 pk;
                pk.x = rneb(acc[0] * inv) | (rneb(acc[1] * inv) << 16);
                pk.y = rneb(acc[2] * inv) | (rneb(acc[3] * inv) << 16);
                pk.z = rneb(acc[4] * inv) | (rneb(acc[5] * inv) << 16);
                pk.w = rneb(acc[6] * inv) | (rneb(acc[7] * inv) << 16);
                *reinterpret_cast<uint4*>(&meanT[(wave * 16 + r) * LP + part * 8]) = pk;
            }
        }
    }
    // No __syncthreads: each wave reads only the LDS rows it wrote.

    // ---- Phase 2: MFMA sweep ----
    const int lo = lane & 15, hi = lane >> 4;
    int arow = row0 + lo;
    if (arow > n - 1) arow = n - 1;
    const size_t abase = (size_t)arow * D;
    const unsigned short* ldsRow = &meanT[(wave * 16 + lo) * LP];

    f32x4 acc[8];
#pragma unroll
    for (int c = 0; c < 8; ++c) acc[c] = (f32x4){0.f, 0.f, 0.f, 0.f};

#pragma unroll
    for (int p = 0; p < 2; ++p) {
        const unsigned short* WF = p ? wfR : wfL;
#pragma unroll
        for (int ks = 0; ks < 4; ++ks) {
            short8 af = p
                ? *reinterpret_cast<const short8*>(feat + abase + ks * 32 + hi * 8)
                : *reinterpret_cast<const short8*>(ldsRow + ks * 32 + hi * 8);
#pragma unroll
            for (int c = 0; c < 8; ++c) {
                short8 bf = *reinterpret_cast<const short8*>(
                    WF + ((((c << 2) | ks) * 64 + lane) << 3));
                acc[c] = __builtin_amdgcn_mfma_f32_16x16x32_bf16(af, bf, acc[c], 0, 0, 0);
            }
        }
    }

    if (mode == 0) {
        // bf16 hidden output
#pragma unroll
        for (int c = 0; c < 8; ++c) {
            const int col = (c << 4) | lo;
            const float bias = bL[col];
#pragma unroll
            for (int j = 0; j < 4; ++j) {
                const int row = row0 + (hi << 2) + j;
                if (row < n)
                    outb[(size_t)row * D + col] =
                        (unsigned short)rneb(fmaxf(acc[c][j] + bias, 0.f));
            }
        }
    } else {
        // fused output projection (round-10 proven epilogue)
        float part2[4][4];
#pragma unroll
        for (int j = 0; j < 4; ++j)
#pragma unroll
            for (int d = 0; d < 4; ++d) part2[j][d] = 0.f;

#pragma unroll
        for (int c = 0; c < 8; ++c) {
            const int col = (c << 4) | lo;
            const float bias = bL[col];
            const float w0 = wsm[0 * D + col];
            const float w1 = wsm[1 * D + col];
            const float w2 = wsm[2 * D + col];
            const float w3 = wsm[3 * D + col];
#pragma unroll
            for (int j = 0; j < 4; ++j) {
                const float h = fmaxf(acc[c][j] + bias, 0.f);
                part2[j][0] += h * w0;
                part2[j][1] += h * w1;
                part2[j][2] += h * w2;
                part2[j][3] += h * w3;
            }
        }

#pragma unroll
        for (int m = 1; m < 16; m <<= 1) {
#pragma unroll
            for (int j = 0; j < 4; ++j)
#pragma unroll
                for (int d = 0; d < 4; ++d)
                    part2[j][d] += __shfl_xor(part2[j][d], m);
        }

        if (lo == 0) {
            const float4 bo = *reinterpret_cast<const float4*>(b_out);
#pragma unroll
            for (int j = 0; j < 4; ++j) {
                const int row = row0 + (hi << 2) + j;
                if (row < n) {
                    float4 o;
                    o.x = part2[j][0] + bo.x;
                    o.y = part2[j][1] + bo.y;
                    o.z = part2[j][2] + bo.z;
                    o.w = part2[j][3] + bo.w;
                    *reinterpret_cast<float4*>(outp + (size_t)row * 4) = o;
                }
            }
        }
    }
}

// ---------------------------------------------------------------------------
extern "C" void kernel_launch(void* const* d_in, const int* in_sizes, int n_in,
                              void* d_out, int out_size, void* d_ws, size_t ws_size,
                              hipStream_t stream)
{
    const float* x    = (const float*)d_in[0];
    const int*   ei   = (const int*)  d_in[1];
    const float* w1l  = (const float*)d_in[2];
    const float* b1l  = (const float*)d_in[3];
    const float* w1r  = (const float*)d_in[4];
    const float* w2l  = (const float*)d_in[5];
    const float* b2l  = (const float*)d_in[6];
    const float* w2r  = (const float*)d_in[7];
    const float* wout = (const float*)d_in[8];
    const float* bout = (const float*)d_in[9];

    const int n = in_sizes[0] / D;       // 100000
    const int E = in_sizes[1] / 2;       // 1600000
    const int* srcI = ei;
    const int* dstI = ei + E;
    const int nbuck = (n + BNODES - 1) >> BSHIFT;   // 196

    auto align256 = [](size_t v) { return (v + 255) & ~(size_t)255; };
    char* base = (char*)d_ws;
    size_t off = 0;
    int* bcnt = (int*)(base + off);            off = align256(off + sizeof(int) * NBUCK_MAX);
    int* bbase = (int*)(base + off);           off = align256(off + sizeof(int) * (NBUCK_MAX + 1));
    int* gcursor = (int*)(base + off);         off = align256(off + sizeof(int) * NBUCK_MAX);
    int* rowptr = (int*)(base + off);          off = align256(off + sizeof(int) * (size_t)(n + 1));
    int* sorted_src = (int*)(base + off);      off = align256(off + sizeof(int) * (size_t)E);
    unsigned* binned = (unsigned*)(base + off); off = align256(off + sizeof(unsigned) * (size_t)E);
    unsigned short* xb = (unsigned short*)(base + off);
    off = align256(off + sizeof(short) * (size_t)n * D);
    unsigned short* bufA = (unsigned short*)(base + off);
    off = align256(off + sizeof(short) * (size_t)n * D);
    unsigned short* wf = (unsigned short*)(base + off);

    // ---- Housekeeping: pack weights, convert x, zero bcnt (round-12 form) ----
    const int n4 = n * (D / 4);
    const int cvtblocks = (n4 + 255) / 256;              // 12500
    misc_kernel<<<32 + cvtblocks, 256, 0, stream>>>(w1l, w1r, w2l, w2r, wf,
                                                    x, xb, n4, bcnt);

    // ---- CSR build (round-12 proven path) ----
    const int ebblocks = (E + 4095) / 4096;              // 391
    bucket_count<<<ebblocks, 256, 0, stream>>>(dstI, bcnt, E, nbuck);
    bucket_scan<<<1, 256, 0, stream>>>(bcnt, bbase, gcursor, nbuck);
    bin_kernel<<<ebblocks, 256, 0, stream>>>(srcI, dstI, gcursor, binned, E, nbuck);
    bucket_build<<<nbuck, 256, 0, stream>>>(binned, bbase, rowptr, sorted_src, n, E);

    const int gblocks = (n + 63) / 64;                   // 1563

    // Layer 1: aggregate+GEMM fused, h1 -> bufA (bf16)
    fused_layer<<<gblocks, 256, 0, stream>>>(
        xb, sorted_src, rowptr, wf, wf + 16384, b1l,
        bufA, wout, bout, nullptr, n, 0);

    // Layer 2: aggregate+GEMM+out_proj fused -> d_out (f32)
    fused_layer<<<gblocks, 256, 0, stream>>>(
        bufA, sorted_src, rowptr, wf + 2 * 16384, wf + 3 * 16384, b2l,
        nullptr, wout, bout, (float*)d_out, n, 1);
}

// Round 19
// 354.454 us; speedup vs baseline: 1.2723x; 1.2723x over previous
//
#include <hip/hip_runtime.h>

constexpr int D = 128;
constexpr int BSHIFT = 9;               // 512 nodes per bucket
constexpr int BNODES = 1 << BSHIFT;
constexpr int NBUCK_MAX = 256;          // n=100000 -> 196 buckets
using short8 = __attribute__((ext_vector_type(8))) short;
using f32x4  = __attribute__((ext_vector_type(4))) float;

__device__ __forceinline__ unsigned rneb(float f) {
    unsigned u = __float_as_uint(f);
    return (u + 0x7fffu + ((u >> 16) & 1u)) >> 16;   // bf16 bits (RNE)
}
__device__ __forceinline__ float lo2f(unsigned u) { return __uint_as_float(u << 16); }
__device__ __forceinline__ float hi2f(unsigned u) { return __uint_as_float(u & 0xffff0000u); }

// ---------------------------------------------------------------------------
// Fused housekeeping: blocks [0,32) pack weight fragments; block 32 also
// zeroes bcnt; blocks [32, 32+12500) convert x to bf16.
// pack: wf[m][f=c*4+ks][lane][i] = W_m[c*16 + (lane&15)][ks*32 + (lane>>4)*8 + i]
__global__ __launch_bounds__(256) void misc_kernel(
    const float* __restrict__ w1l, const float* __restrict__ w1r,
    const float* __restrict__ w2l, const float* __restrict__ w2r,
    unsigned short* __restrict__ wf,
    const float* __restrict__ x, unsigned short* __restrict__ xb, int n4,
    int* __restrict__ bcnt)
{
    if (blockIdx.x < 32) {
        int t = blockIdx.x * 256 + threadIdx.x;          // 8192 threads
        int m = t >> 11;
        int r = t & 2047;                                 // f*64 + lane
        int f = r >> 6, lane = r & 63;
        int c = f >> 2, ks = f & 3;
        int col = c * 16 + (lane & 15);
        int k0 = ks * 32 + (lane >> 4) * 8;
        const float* W = (m == 0) ? w1l : (m == 1) ? w1r : (m == 2) ? w2l : w2r;
        unsigned short o[8];
#pragma unroll
        for (int i = 0; i < 8; ++i) o[i] = (unsigned short)rneb(W[col * D + k0 + i]);
        uint4 pk;
        pk.x = o[0] | ((unsigned)o[1] << 16);
        pk.y = o[2] | ((unsigned)o[3] << 16);
        pk.z = o[4] | ((unsigned)o[5] << 16);
        pk.w = o[6] | ((unsigned)o[7] << 16);
        reinterpret_cast<uint4*>(wf)[t] = pk;
        return;
    }
    if (blockIdx.x == 32) bcnt[threadIdx.x] = 0;          // NBUCK_MAX == 256
    int i = (blockIdx.x - 32) * 256 + threadIdx.x;
    if (i >= n4) return;
    float4 v = reinterpret_cast<const float4*>(x)[i];
    uint2 o;
    o.x = rneb(v.x) | (rneb(v.y) << 16);
    o.y = rneb(v.z) | (rneb(v.w) << 16);
    reinterpret_cast<uint2*>(xb)[i] = o;
}

// ---------------------------------------------------------------------------
// Pass 1: per-bucket edge counts (LDS hist per block, 1 global atomic per
// (block,bucket)).
__global__ __launch_bounds__(256) void bucket_count(
    const int* __restrict__ dstI, int* __restrict__ bcnt, int E, int nb)
{
    __shared__ int lh[NBUCK_MAX];
    const int t = threadIdx.x;
    const int e0 = blockIdx.x * 4096;
    for (int i = t; i < nb; i += 256) lh[i] = 0;
    __syncthreads();
#pragma unroll
    for (int q = 0; q < 16; ++q) {
        int e = e0 + q * 256 + t;
        if (e < E) atomicAdd(&lh[dstI[e] >> BSHIFT], 1);
    }
    __syncthreads();
    for (int b = t; b < nb; b += 256)
        if (lh[b] > 0) atomicAdd(&bcnt[b], lh[b]);
}

// Pass 2: scan bucket counts -> bucket base offsets + bin cursors.
__global__ __launch_bounds__(256) void bucket_scan(
    const int* __restrict__ bcnt, int* __restrict__ bbase,
    int* __restrict__ gcursor, int nb)
{
    __shared__ int tmp[256];
    const int t = threadIdx.x;
    const int v = (t < nb) ? bcnt[t] : 0;
    tmp[t] = v;
    __syncthreads();
    for (int off = 1; off < 256; off <<= 1) {
        int u = (t >= off) ? tmp[t - off] : 0;
        __syncthreads();
        tmp[t] += u;
        __syncthreads();
    }
    int excl = tmp[t] - v;
    if (t < nb) { bbase[t] = excl; gcursor[t] = excl; }
    if (t == nb - 1) bbase[nb] = excl + v;
}

// Pass 3: bin edges into bucket-contiguous runs. Packed word =
// src | (dst & 511) << 17.   (src < 2^17, n = 100000)
__global__ __launch_bounds__(256) void bin_kernel(
    const int* __restrict__ srcI, const int* __restrict__ dstI,
    int* __restrict__ gcursor, unsigned* __restrict__ binned, int E, int nb)
{
    __shared__ int lhist[NBUCK_MAX];
    __shared__ int lbase[NBUCK_MAX];
    __shared__ int lcnt[NBUCK_MAX];
    const int t = threadIdx.x;
    const int e0 = blockIdx.x * 4096;
    for (int i = t; i < nb; i += 256) { lhist[i] = 0; lcnt[i] = 0; }
    __syncthreads();

    int dcache[16], scache[16];
#pragma unroll
    for (int q = 0; q < 16; ++q) {
        int e = e0 + q * 256 + t;
        int d = (e < E) ? dstI[e] : -1;
        dcache[q] = d;
        scache[q] = (e < E) ? srcI[e] : 0;
        if (d >= 0) atomicAdd(&lhist[d >> BSHIFT], 1);
    }
    __syncthreads();
    for (int b = t; b < nb; b += 256)
        if (lhist[b] > 0) lbase[b] = atomicAdd(&gcursor[b], lhist[b]);
    __syncthreads();
#pragma unroll
    for (int q = 0; q < 16; ++q) {
        int d = dcache[q];
        if (d >= 0) {
            int b = d >> BSHIFT;
            int off = atomicAdd(&lcnt[b], 1);
            binned[lbase[b] + off] =
                (unsigned)scache[q] | ((unsigned)(d & (BNODES - 1)) << 17);
        }
    }
}

// Pass 4: one block per bucket. LDS histogram of the bucket's 512 nodes,
// LDS scan -> rowptr slice, then LDS-cursor scatter -> sorted_src.
__global__ __launch_bounds__(256) void bucket_build(
    const unsigned* __restrict__ binned, const int* __restrict__ bbase,
    int* __restrict__ rowptr, int* __restrict__ sorted_src, int n, int E)
{
    __shared__ int hist[BNODES];
    __shared__ int cur[BNODES];
    __shared__ int tmp[256];
    const int t = threadIdx.x;
    const int b = blockIdx.x;
    const int node0 = b << BSHIFT;
    const int ebeg = bbase[b];
    const int eend = bbase[b + 1];

    hist[t] = 0; hist[t + 256] = 0;
    __syncthreads();
    for (int e = ebeg + t; e < eend; e += 256)
        atomicAdd(&hist[(binned[e] >> 17) & (BNODES - 1)], 1);
    __syncthreads();

    const int v0 = hist[2 * t], v1 = hist[2 * t + 1];
    const int s = v0 + v1;
    tmp[t] = s;
    __syncthreads();
    for (int off = 1; off < 256; off <<= 1) {
        int u = (t >= off) ? tmp[t - off] : 0;
        __syncthreads();
        tmp[t] += u;
        __syncthreads();
    }
    const int pre = ebeg + tmp[t] - s;       // exclusive prefix of node 2t
    const int i0 = node0 + 2 * t, i1 = i0 + 1;
    cur[2 * t] = pre;
    cur[2 * t + 1] = pre + v0;
    if (i0 < n) rowptr[i0] = pre;
    if (i1 < n) rowptr[i1] = pre + v0;
    if (b == 0 && t == 0) rowptr[n] = E;
    __syncthreads();

    for (int e = ebeg + t; e < eend; e += 256) {
        unsigned w = binned[e];
        int pos = atomicAdd(&cur[(w >> 17) & (BNODES - 1)], 1);
        sorted_src[pos] = (int)(w & 0x1FFFF);
    }
}

// ---------------------------------------------------------------------------
// Gather-mean aggregation: one 64-lane wave per node; lane = (sub = lane>>4,
// part = lane&15); each lane loads dwordx4 (8 bf16) of row src[e+sub] at
// column slice part*8. 16-edge main loop keeps 4 feature loads in flight.
// Cross-sub reduce via shfl_xor(16|32) at the end.
__global__ __launch_bounds__(256) void aggregate_bf16(
    const unsigned short* __restrict__ feat, const int* __restrict__ sorted_src,
    const int* __restrict__ rowptr, unsigned short* __restrict__ outb, int n)
{
    const int wid = (blockIdx.x * 256 + threadIdx.x) >> 6;
    if (wid >= n) return;
    const int lane = threadIdx.x & 63;
    const int sub = lane >> 4;
    const int part = lane & 15;
    const int beg = rowptr[wid];
    const int end = rowptr[wid + 1];
    const int deg = end - beg;

    float acc[8];
#pragma unroll
    for (int j = 0; j < 8; ++j) acc[j] = 0.f;

    int e = beg;
    // 16 edges per iteration: 4 independent dwordx4 streams in flight.
    for (; e + 16 <= end; e += 16) {
        const int s0 = sorted_src[e + sub];
        const int s1 = sorted_src[e + 4 + sub];
        const int s2 = sorted_src[e + 8 + sub];
        const int s3 = sorted_src[e + 12 + sub];
        const uint4 v0 = *reinterpret_cast<const uint4*>(feat + (size_t)s0 * D + part * 8);
        const uint4 v1 = *reinterpret_cast<const uint4*>(feat + (size_t)s1 * D + part * 8);
        const uint4 v2 = *reinterpret_cast<const uint4*>(feat + (size_t)s2 * D + part * 8);
        const uint4 v3 = *reinterpret_cast<const uint4*>(feat + (size_t)s3 * D + part * 8);
        acc[0] += lo2f(v0.x); acc[1] += hi2f(v0.x);
        acc[2] += lo2f(v0.y); acc[3] += hi2f(v0.y);
        acc[4] += lo2f(v0.z); acc[5] += hi2f(v0.z);
        acc[6] += lo2f(v0.w); acc[7] += hi2f(v0.w);
        acc[0] += lo2f(v1.x); acc[1] += hi2f(v1.x);
        acc[2] += lo2f(v1.y); acc[3] += hi2f(v1.y);
        acc[4] += lo2f(v1.z); acc[5] += hi2f(v1.z);
        acc[6] += lo2f(v1.w); acc[7] += hi2f(v1.w);
        acc[0] += lo2f(v2.x); acc[1] += hi2f(v2.x);
        acc[2] += lo2f(v2.y); acc[3] += hi2f(v2.y);
        acc[4] += lo2f(v2.z); acc[5] += hi2f(v2.z);
        acc[6] += lo2f(v2.w); acc[7] += hi2f(v2.w);
        acc[0] += lo2f(v3.x); acc[1] += hi2f(v3.x);
        acc[2] += lo2f(v3.y); acc[3] += hi2f(v3.y);
        acc[4] += lo2f(v3.z); acc[5] += hi2f(v3.z);
        acc[6] += lo2f(v3.w); acc[7] += hi2f(v3.w);
    }
    if (e + 8 <= end) {
        const int s0 = sorted_src[e + sub];
        const int s1 = sorted_src[e + 4 + sub];
        const uint4 v0 = *reinterpret_cast<const uint4*>(feat + (size_t)s0 * D + part * 8);
        const uint4 v1 = *reinterpret_cast<const uint4*>(feat + (size_t)s1 * D + part * 8);
        acc[0] += lo2f(v0.x); acc[1] += hi2f(v0.x);
        acc[2] += lo2f(v0.y); acc[3] += hi2f(v0.y);
        acc[4] += lo2f(v0.z); acc[5] += hi2f(v0.z);
        acc[6] += lo2f(v0.w); acc[7] += hi2f(v0.w);
        acc[0] += lo2f(v1.x); acc[1] += hi2f(v1.x);
        acc[2] += lo2f(v1.y); acc[3] += hi2f(v1.y);
        acc[4] += lo2f(v1.z); acc[5] += hi2f(v1.z);
        acc[6] += lo2f(v1.w); acc[7] += hi2f(v1.w);
        e += 8;
    }
    if (e + 4 <= end) {
        const int s0 = sorted_src[e + sub];
        const uint4 v0 = *reinterpret_cast<const uint4*>(feat + (size_t)s0 * D + part * 8);
        acc[0] += lo2f(v0.x); acc[1] += hi2f(v0.x);
        acc[2] += lo2f(v0.y); acc[3] += hi2f(v0.y);
        acc[4] += lo2f(v0.z); acc[5] += hi2f(v0.z);
        acc[6] += lo2f(v0.w); acc[7] += hi2f(v0.w);
        e += 4;
    }
    if (e < end) {
        const int ei = e + sub;
        const bool act = ei < end;
        const int s = act ? sorted_src[ei] : sorted_src[beg];
        const float m = act ? 1.f : 0.f;
        const uint4 v = *reinterpret_cast<const uint4*>(feat + (size_t)s * D + part * 8);
        acc[0] += m * lo2f(v.x); acc[1] += m * hi2f(v.x);
        acc[2] += m * lo2f(v.y); acc[3] += m * hi2f(v.y);
        acc[4] += m * lo2f(v.z); acc[5] += m * hi2f(v.z);
        acc[6] += m * lo2f(v.w); acc[7] += m * hi2f(v.w);
    }

#pragma unroll
    for (int j = 0; j < 8; ++j) {
        acc[j] += __shfl_xor(acc[j], 16);
        acc[j] += __shfl_xor(acc[j], 32);
    }

    if (sub == 0) {
        const float inv = (deg > 0) ? 1.0f / (float)deg : 0.f;
        uint4 pk;
        pk.x = rneb(acc[0] * inv) | (rneb(acc[1] * inv) << 16);
        pk.y = rneb(acc[2] * inv) | (rneb(acc[3] * inv) << 16);
        pk.z = rneb(acc[4] * inv) | (rneb(acc[5] * inv) << 16);
        pk.w = rneb(acc[6] * inv) | (rneb(acc[7] * inv) << 16);
        *reinterpret_cast<uint4*>(outb + (size_t)wid * D + part * 8) = pk;
    }
}

// ---------------------------------------------------------------------------
// Layer-1 fused SAGE via bf16 MFMA (no LDS):
// out[i][j] = relu( mean[i]@WL^T + bL + self[i]@WR^T ) -> bf16
__global__ __launch_bounds__(256) void mfma_gemm(
    const unsigned short* __restrict__ aMean, const unsigned short* __restrict__ aSelf,
    const unsigned short* __restrict__ wfL, const unsigned short* __restrict__ wfR,
    const float* __restrict__ bL, unsigned short* __restrict__ outb, int n)
{
    const int lane = threadIdx.x & 63;
    const int wave = threadIdx.x >> 6;
    const int lo = lane & 15, hi = lane >> 4;
    const int row0 = blockIdx.x * 64 + wave * 16;
    int arow = row0 + lo;
    if (arow > n - 1) arow = n - 1;
    const size_t abase = (size_t)arow * D;

    f32x4 acc[8];
#pragma unroll
    for (int c = 0; c < 8; ++c) acc[c] = (f32x4){0.f, 0.f, 0.f, 0.f};

#pragma unroll
    for (int p = 0; p < 2; ++p) {
        const unsigned short* A  = p ? aSelf : aMean;
        const unsigned short* WF = p ? wfR : wfL;
#pragma unroll
        for (int ks = 0; ks < 4; ++ks) {
            short8 af = *reinterpret_cast<const short8*>(A + abase + ks * 32 + hi * 8);
#pragma unroll
            for (int c = 0; c < 8; ++c) {
                short8 bf = *reinterpret_cast<const short8*>(
                    WF + ((((c << 2) | ks) * 64 + lane) << 3));
                acc[c] = __builtin_amdgcn_mfma_f32_16x16x32_bf16(af, bf, acc[c], 0, 0, 0);
            }
        }
    }

#pragma unroll
    for (int c = 0; c < 8; ++c) {
        const int col = (c << 4) | lo;
        const float bias = bL[col];
#pragma unroll
        for (int j = 0; j < 4; ++j) {
            const int row = row0 + (hi << 2) + j;
            if (row < n)
                outb[(size_t)row * D + col] =
                    (unsigned short)rneb(fmaxf(acc[c][j] + bias, 0.f));
        }
    }
}

// ---------------------------------------------------------------------------
// Layer-2 fused SAGE + output projection:
// h2[i][:] = relu( mean[i]@WL^T + bL + self[i]@WR^T )  (registers, f32)
// out[i][d] = h2[i][:] . w_out[d][:] + b_out[d]        (d_out = 4)
__global__ __launch_bounds__(256) void mfma_gemm_out(
    const unsigned short* __restrict__ aMean, const unsigned short* __restrict__ aSelf,
    const unsigned short* __restrict__ wfL, const unsigned short* __restrict__ wfR,
    const float* __restrict__ bL, const float* __restrict__ w_out,
    const float* __restrict__ b_out, float* __restrict__ outp, int n)
{
    __shared__ float wsm[4 * D];
    wsm[threadIdx.x] = w_out[threadIdx.x];
    wsm[threadIdx.x + 256] = w_out[threadIdx.x + 256];
    __syncthreads();

    const int lane = threadIdx.x & 63;
    const int wave = threadIdx.x >> 6;
    const int lo = lane & 15, hi = lane >> 4;
    const int row0 = blockIdx.x * 64 + wave * 16;
    int arow = row0 + lo;
    if (arow > n - 1) arow = n - 1;
    const size_t abase = (size_t)arow * D;

    f32x4 acc[8];
#pragma unroll
    for (int c = 0; c < 8; ++c) acc[c] = (f32x4){0.f, 0.f, 0.f, 0.f};

#pragma unroll
    for (int p = 0; p < 2; ++p) {
        const unsigned short* A  = p ? aSelf : aMean;
        const unsigned short* WF = p ? wfR : wfL;
#pragma unroll
        for (int ks = 0; ks < 4; ++ks) {
            short8 af = *reinterpret_cast<const short8*>(A + abase + ks * 32 + hi * 8);
#pragma unroll
            for (int c = 0; c < 8; ++c) {
                short8 bf = *reinterpret_cast<const short8*>(
                    WF + ((((c << 2) | ks) * 64 + lane) << 3));
                acc[c] = __builtin_amdgcn_mfma_f32_16x16x32_bf16(af, bf, acc[c], 0, 0, 0);
            }
        }
    }

    // Epilogue: relu + project to 4 dims, reduce across the 16-lane lo group.
    float part[4][4];
#pragma unroll
    for (int j = 0; j < 4; ++j)
#pragma unroll
        for (int d = 0; d < 4; ++d) part[j][d] = 0.f;

#pragma unroll
    for (int c = 0; c < 8; ++c) {
        const int col = (c << 4) | lo;
        const float bias = bL[col];
        const float w0 = wsm[0 * D + col];
        const float w1 = wsm[1 * D + col];
        const float w2 = wsm[2 * D + col];
        const float w3 = wsm[3 * D + col];
#pragma unroll
        for (int j = 0; j < 4; ++j) {
            const float h = fmaxf(acc[c][j] + bias, 0.f);
            part[j][0] += h * w0;
            part[j][1] += h * w1;
            part[j][2] += h * w2;
            part[j][3] += h * w3;
        }
    }

#pragma unroll
    for (int m = 1; m < 16; m <<= 1) {
#pragma unroll
        for (int j = 0; j < 4; ++j)
#pragma unroll
            for (int d = 0; d < 4; ++d)
                part[j][d] += __shfl_xor(part[j][d], m);
    }

    if (lo == 0) {
        const float4 bo = *reinterpret_cast<const float4*>(b_out);
#pragma unroll
        for (int j = 0; j < 4; ++j) {
            const int row = row0 + (hi << 2) + j;
            if (row < n) {
                float4 o;
                o.x = part[j][0] + bo.x;
                o.y = part[j][1] + bo.y;
                o.z = part[j][2] + bo.z;
                o.w = part[j][3] + bo.w;
                *reinterpret_cast<float4*>(outp + (size_t)row * 4) = o;
            }
        }
    }
}

// ---------------------------------------------------------------------------
extern "C" void kernel_launch(void* const* d_in, const int* in_sizes, int n_in,
                              void* d_out, int out_size, void* d_ws, size_t ws_size,
                              hipStream_t stream)
{
    const float* x    = (const float*)d_in[0];
    const int*   ei   = (const int*)  d_in[1];
    const float* w1l  = (const float*)d_in[2];
    const float* b1l  = (const float*)d_in[3];
    const float* w1r  = (const float*)d_in[4];
    const float* w2l  = (const float*)d_in[5];
    const float* b2l  = (const float*)d_in[6];
    const float* w2r  = (const float*)d_in[7];
    const float* wout = (const float*)d_in[8];
    const float* bout = (const float*)d_in[9];

    const int n = in_sizes[0] / D;       // 100000
    const int E = in_sizes[1] / 2;       // 1600000
    const int* srcI = ei;
    const int* dstI = ei + E;
    const int nbuck = (n + BNODES - 1) >> BSHIFT;   // 196

    auto align256 = [](size_t v) { return (v + 255) & ~(size_t)255; };
    char* base = (char*)d_ws;
    size_t off = 0;
    int* bcnt = (int*)(base + off);            off = align256(off + sizeof(int) * NBUCK_MAX);
    int* bbase = (int*)(base + off);           off = align256(off + sizeof(int) * (NBUCK_MAX + 1));
    int* gcursor = (int*)(base + off);         off = align256(off + sizeof(int) * NBUCK_MAX);
    int* rowptr = (int*)(base + off);          off = align256(off + sizeof(int) * (size_t)(n + 1));
    int* sorted_src = (int*)(base + off);      off = align256(off + sizeof(int) * (size_t)E);
    unsigned* binned = (unsigned*)(base + off); off = align256(off + sizeof(unsigned) * (size_t)E);
    unsigned short* xb = (unsigned short*)(base + off);
    off = align256(off + sizeof(short) * (size_t)n * D);
    unsigned short* bufA = (unsigned short*)(base + off);
    off = align256(off + sizeof(short) * (size_t)n * D);
    unsigned short* bufB = (unsigned short*)(base + off);
    off = align256(off + sizeof(short) * (size_t)n * D);
    unsigned short* wf = (unsigned short*)(base + off);

    // ---- Housekeeping: pack weights, convert x, zero bcnt ----
    const int n4 = n * (D / 4);
    const int cvtblocks = (n4 + 255) / 256;              // 12500
    misc_kernel<<<32 + cvtblocks, 256, 0, stream>>>(w1l, w1r, w2l, w2r, wf,
                                                    x, xb, n4, bcnt);

    // ---- CSR build (once; reused by both layers) ----
    const int ebblocks = (E + 4095) / 4096;              // 391
    bucket_count<<<ebblocks, 256, 0, stream>>>(dstI, bcnt, E, nbuck);
    bucket_scan<<<1, 256, 0, stream>>>(bcnt, bbase, gcursor, nbuck);
    bin_kernel<<<ebblocks, 256, 0, stream>>>(srcI, dstI, gcursor, binned, E, nbuck);
    bucket_build<<<nbuck, 256, 0, stream>>>(binned, bbase, rowptr, sorted_src, n, E);

    const int ablocks = (int)(((long long)n * 64 + 255) / 256);
    const int gblocks = (n + 63) / 64;

    // Layer 1
    aggregate_bf16<<<ablocks, 256, 0, stream>>>(xb, sorted_src, rowptr, bufA, n);
    mfma_gemm<<<gblocks, 256, 0, stream>>>(bufA, xb, wf, wf + 16384, b1l, bufA, n);

    // Layer 2 (+ fused output projection)
    aggregate_bf16<<<ablocks, 256, 0, stream>>>(bufA, sorted_src, rowptr, bufB, n);
    mfma_gemm_out<<<gblocks, 256, 0, stream>>>(bufB, bufA, wf + 2 * 16384, wf + 3 * 16384,
                                               b2l, wout, bout, (float*)d_out, n);
}